// Round 2
// baseline (503.465 us; speedup 1.0000x reference)
//
#include <hip/hip_runtime.h>
#include <hip/hip_bf16.h>
#include <stdint.h>
#include <stddef.h>

typedef __attribute__((ext_vector_type(8))) short short8;
typedef __attribute__((ext_vector_type(4))) float f32x4;

#define NTOK 32768
#define DIN 512
#define HID 1024
#define DOUT 256
#define NEXP 10

__device__ __forceinline__ unsigned short f2bf(float f) {
  unsigned int u = __float_as_uint(f);
  u += 0x7fffu + ((u >> 16) & 1u);   // round-to-nearest-even
  return (unsigned short)(u >> 16);
}

// async 16B/lane global->LDS DMA (dest = wave-uniform base + lane*16)
__device__ __forceinline__ void gld16(void* lds, const void* g) {
  __builtin_amdgcn_global_load_lds(
      (const __attribute__((address_space(1))) unsigned int*)g,
      (__attribute__((address_space(3))) unsigned int*)lds, 16, 0, 0);
}

// ---------------- Wr transpose: [512][10] f32 -> [10][512] f32 -------------
__global__ __launch_bounds__(256) void k_transpose_wr(
    const float* __restrict__ wr, float* __restrict__ wrt) {
  int i = blockIdx.x * 256 + threadIdx.x;
  if (i < DIN * NEXP) {
    int d = i / NEXP, e = i % NEXP;
    wrt[e * DIN + d] = wr[i];
  }
}

// ---------- generic [E][R][C] f32 -> [E][C][R] bf16 (ushort bits) ----------
__global__ __launch_bounds__(256) void k_transpose_conv(
    const float* __restrict__ in, unsigned short* __restrict__ out, int R, int C) {
  __shared__ unsigned short tile[64][72];
  int tid = threadIdx.x;
  const float* ip = in + ((size_t)blockIdx.z * R + blockIdx.y * 64) * C + blockIdx.x * 64;
  int r = tid >> 2, c0 = (tid & 3) * 16;
  const float* p = ip + (size_t)r * C + c0;
#pragma unroll
  for (int j = 0; j < 16; j += 4) {
    float4 v = *(const float4*)(p + j);
    tile[r][c0 + j + 0] = f2bf(v.x);
    tile[r][c0 + j + 1] = f2bf(v.y);
    tile[r][c0 + j + 2] = f2bf(v.z);
    tile[r][c0 + j + 3] = f2bf(v.w);
  }
  __syncthreads();
  unsigned short* op = out + ((size_t)blockIdx.z * C + blockIdx.x * 64) * R + blockIdx.y * 64;
  int c = tid >> 2, r0 = (tid & 3) * 16;
  unsigned short* q = op + (size_t)c * R + r0;
  union { short8 v; unsigned short u[8]; } t0, t1;
#pragma unroll
  for (int j = 0; j < 8; j++) { t0.u[j] = tile[r0 + j][c]; t1.u[j] = tile[r0 + 8 + j][c]; }
  *(short8*)(q) = t0.v;
  *(short8*)(q + 8) = t1.v;
}

// ----------------- router: logits, softmax, top-2, expert lists ------------
__global__ __launch_bounds__(256) void k_router(
    const float* __restrict__ x, const float* __restrict__ spike,
    const float* __restrict__ wrt, const float* __restrict__ br,
    unsigned short* __restrict__ xb, int* __restrict__ cnt,
    int* __restrict__ tok, float* __restrict__ wgt) {
  __shared__ int s_i0[64], s_i1[64];
  __shared__ float s_w0[64], s_w1[64];
  __shared__ int hist[NEXP], base_[NEXP], loc[NEXP];
  int tid = threadIdx.x, wave = tid >> 6, lane = tid & 63;
  if (tid < NEXP) { hist[tid] = 0; loc[tid] = 0; }
  __syncthreads();
  for (int t = 0; t < 16; t++) {
    int slot = wave * 16 + t;
    int b = blockIdx.x * 64 + slot;
    const float* xr = x + (size_t)b * DIN;
    float xv[8];
#pragma unroll
    for (int k = 0; k < 8; k++) xv[k] = xr[lane + 64 * k];   // coalesced
    unsigned short* xo = xb + (size_t)b * DIN;
#pragma unroll
    for (int k = 0; k < 8; k++) xo[lane + 64 * k] = f2bf(xv[k]);
    float lg[NEXP];
#pragma unroll
    for (int e = 0; e < NEXP; e++) {
      const float* w = wrt + e * DIN;
      float s = 0.f;
#pragma unroll
      for (int k = 0; k < 8; k++) s += xv[k] * w[lane + 64 * k];
      lg[e] = s;
    }
#pragma unroll
    for (int off = 32; off > 0; off >>= 1) {
#pragma unroll
      for (int e = 0; e < NEXP; e++) lg[e] += __shfl_xor(lg[e], off);
    }
    float sv = spike[(size_t)b * 16 + (lane & 15)];
    sv += __shfl_xor(sv, 8); sv += __shfl_xor(sv, 4);
    sv += __shfl_xor(sv, 2); sv += __shfl_xor(sv, 1);
    float avg = sv * 0.0625f;
#pragma unroll
    for (int e = 0; e < NEXP; e++) lg[e] += br[e];
    lg[8] += avg; lg[9] += avg;
    float mx = lg[0];
#pragma unroll
    for (int e = 1; e < NEXP; e++) mx = fmaxf(mx, lg[e]);
    float p[NEXP], ps = 0.f;
#pragma unroll
    for (int e = 0; e < NEXP; e++) { p[e] = __expf(lg[e] - mx); ps += p[e]; }
    int i0 = 0; float p0 = p[0];
#pragma unroll
    for (int e = 1; e < NEXP; e++) if (p[e] > p0) { p0 = p[e]; i0 = e; }
    float p1 = -1.f; int i1 = 0;
#pragma unroll
    for (int e = 0; e < NEXP; e++) if (e != i0 && p[e] > p1) { p1 = p[e]; i1 = e; }
    float inv = 1.f / (p0 + p1 + ps * 1e-9f);
    if (lane == 0) {
      s_i0[slot] = i0; s_i1[slot] = i1;
      s_w0[slot] = p0 * inv; s_w1[slot] = p1 * inv;
      atomicAdd(&hist[i0], 1); atomicAdd(&hist[i1], 1);
    }
  }
  __syncthreads();
  if (tid < NEXP) base_[tid] = atomicAdd(&cnt[tid], hist[tid]);
  __syncthreads();
  if (tid < 64) {
    int b = blockIdx.x * 64 + tid;
    int i0 = s_i0[tid], i1 = s_i1[tid];
    int s0 = base_[i0] + atomicAdd(&loc[i0], 1);
    tok[i0 * NTOK + s0] = b; wgt[i0 * NTOK + s0] = s_w0[tid];
    int s1 = base_[i1] + atomicAdd(&loc[i1], 1);
    tok[i1 * NTOK + s1] = b; wgt[i1 * NTOK + s1] = s_w1[tid];
  }
}

// --------- fused grouped expert kernel: out += w * (relu(x W1 + b1) W2 + b2)
// T3/T4 pipeline: per round r -> { s_waitcnt vmcnt(N) lgkmcnt(0); s_barrier;
// issue batch r+2; compute batch r }. Triple-buffered staging, counted waits
// (never drain-0 in the loop), 2-phase cover per batch, one barrier/round.
// Tile M=128 tok x N=256 out, hidden chunk HC=64 (16 chunks), BK=64 (GEMM1),
// K2=32 (GEMM2, 2 rounds/chunk). 8 waves (2 tok-halves x 4 N-quarters).
// LDS = 3x16K(X) + 3x8K(W1) + 3x16K(W2) + 16K(h) = 136 KB -> 1 block/CU.
__global__ __launch_bounds__(512, 2) void k_moe(
    const unsigned short* __restrict__ xb, const unsigned short* __restrict__ w1t,
    const unsigned short* __restrict__ w2t, const float* __restrict__ b1,
    const float* __restrict__ b2, const int* __restrict__ cnt,
    const int* __restrict__ tok, const float* __restrict__ wgt,
    float* __restrict__ out) {
  int e = blockIdx.y;
  int n = cnt[e];
  int tile = blockIdx.x;
  if (tile * 128 >= n) return;
  __shared__ unsigned short xa[3][8192];    // 3 x 16 KB  X  [128 tok x 64 k]
  __shared__ unsigned short w1s[3][4096];   // 3 x  8 KB  W1 [ 64 h   x 64 k]
  __shared__ unsigned short w2s[3][8192];   // 3 x 16 KB  W2 [256 o   x 32 h] pair-row
  __shared__ unsigned short hs[8192];       //     16 KB  h  [128 tok x 64 h]
  __shared__ int stok[128];
  __shared__ float swgt[128];
  int tid = threadIdx.x;
  if (tid < 128) {
    int idx = tile * 128 + tid;
    bool v = idx < n;
    stok[tid] = v ? tok[e * NTOK + idx] : 0;
    swgt[tid] = v ? wgt[e * NTOK + idx] : 0.f;
  }
  __syncthreads();
  int wave = tid >> 6, lane = tid & 63, quad = lane >> 4, l16 = lane & 15;
  int wm = wave & 1, wn = wave >> 1;            // wm: token half, wn: N quarter
  // ---- staging constants
  int srow = tid >> 3;                          // 0..63
  int sc8 = (tid & 7) ^ (srow & 7);             // inverse XOR swizzle on source
  const unsigned short* w1e = w1t + (size_t)e * HID * DIN;   // [h][d]
  const unsigned short* w2e = w2t + (size_t)e * DOUT * HID;  // [o][h]
  const unsigned short* gxA = xb + (size_t)stok[srow] * DIN + sc8 * 8;
  const unsigned short* gxB = xb + (size_t)stok[64 + srow] * DIN + sc8 * 8;
  const unsigned short* g1A = w1e + (size_t)srow * DIN + sc8 * 8;
  // W2 pair-row: slot s -> o = 2*(s>>3) + (v>>2), h-chunk = v&3, v = (s&7)^((s>>3)&7)
  const unsigned short* g2A = w2e + (size_t)(2 * srow + (sc8 >> 2)) * HID + (sc8 & 3) * 8;

  // ---- ALL scalar VMEM before the pipeline (keeps vmcnt FIFO = gld16 only)
  float bb[16];
#pragma unroll
  for (int h = 0; h < 16; h++) bb[h] = b1[e * HID + h * 64 + wn * 16 + l16];
  f32x4 acc2[4][4];
#pragma unroll
  for (int nt = 0; nt < 4; nt++) {
    float bv = b2[e * DOUT + wn * 64 + nt * 16 + l16];
    acc2[0][nt] = (f32x4){bv, bv, bv, bv};
    acc2[1][nt] = (f32x4){bv, bv, bv, bv};
    acc2[2][nt] = (f32x4){bv, bv, bv, bv};
    acc2[3][nt] = (f32x4){bv, bv, bv, bv};
  }

#define ISS_G(buf, hcv, ks) do { \
    gld16(&xa[buf][(unsigned)tid * 8], gxA + (ks) * 64); \
    gld16(&xa[buf][((unsigned)tid + 512) * 8], gxB + (ks) * 64); \
    gld16(&w1s[buf][(unsigned)tid * 8], g1A + (size_t)(hcv) * 64 * DIN + (ks) * 64); \
  } while (0)
#define ISS_V(buf, hcv, j) do { \
    const unsigned short* p_ = g2A + (hcv) * 64 + (j) * 32; \
    gld16(&w2s[buf][(unsigned)tid * 8], p_); \
    gld16(&w2s[buf][((unsigned)tid + 512) * 8], p_ + 128 * HID); \
  } while (0)
// counted wait (own batch landed; next batch stays in flight) + barrier
#define PWAIT(N) do { \
    asm volatile("s_waitcnt vmcnt(" #N ") lgkmcnt(0)" ::: "memory"); \
    __builtin_amdgcn_s_barrier(); \
    __builtin_amdgcn_sched_barrier(0); \
  } while (0)

  // ---- prologue: issue G(0,0), G(0,1)
  ISS_G(0, 0, 0);
  ISS_G(1, 0, 1);

  for (int hc = 0; hc < 16; hc++) {
    int g0 = (hc * 8) % 3;        // buffer of G(hc,0)
    int v0 = (hc * 2) % 3;        // buffer of V(hc,0)
    int hcn = hc < 15 ? hc + 1 : 15;   // hc=15: redundant re-stage (safe, unread)
    f32x4 acc1[4];
#pragma unroll
    for (int mt = 0; mt < 4; mt++) acc1[mt] = (f32x4){0.f, 0.f, 0.f, 0.f};
    // ============ GEMM1: h[128x64] = x[128x512] @ W1T-chunk, 8 rounds =======
#pragma unroll
    for (int ks = 0; ks < 8; ks++) {
      // wait: batch(G ks) landed; leaves next batch (3 loads / 2 for V0) in flight
      if (ks < 7) { PWAIT(3); } else { PWAIT(2); }
      // issue batch r+2
      if (ks < 6)       ISS_G((g0 + ks + 2) % 3, hc, ks + 2);
      else if (ks == 6) ISS_V(v0, hc, 0);
      else              ISS_V((v0 + 1) % 3, hc, 1);
      const unsigned short* xab = xa[(g0 + ks) % 3];
      const unsigned short* w1b = w1s[(g0 + ks) % 3];
      __builtin_amdgcn_s_setprio(1);
#pragma unroll
      for (int ki2 = 0; ki2 < 2; ki2++) {
        int cq = ki2 * 4 + quad;
        short8 af[4], bfr;
#pragma unroll
        for (int mt = 0; mt < 4; mt++) {
          int r = wm * 64 + mt * 16 + l16;
          af[mt] = *(const short8*)(xab + ((unsigned)(r * 8 + (cq ^ (r & 7)))) * 8);
        }
        {
          int r = wn * 16 + l16;
          bfr = *(const short8*)(w1b + ((unsigned)(r * 8 + (cq ^ (r & 7)))) * 8);
        }
#pragma unroll
        for (int mt = 0; mt < 4; mt++)
          acc1[mt] = __builtin_amdgcn_mfma_f32_16x16x32_bf16(af[mt], bfr, acc1[mt], 0, 0, 0);
      }
      __builtin_amdgcn_s_setprio(0);
      if (ks == 7) {
        // bias + relu + bf16 -> swizzled h LDS (visible after next PWAIT's lgkmcnt+bar)
        float bbv = bb[hc];
        int col = wn * 16 + l16;
        int c16 = col >> 3, co = col & 7;
#pragma unroll
        for (int mt = 0; mt < 4; mt++) {
#pragma unroll
          for (int r4 = 0; r4 < 4; r4++) {
            int r = wm * 64 + mt * 16 + quad * 4 + r4;
            float v = acc1[mt][r4] + bbv;
            hs[((unsigned)(r * 8 + (c16 ^ (r & 7)))) * 8 + co] = f2bf(v > 0.f ? v : 0.f);
          }
        }
      }
    }
    // ============ GEMM2: out[128x256] += h @ W2T-chunk, 2 rounds (K=32) =====
#pragma unroll
    for (int j = 0; j < 2; j++) {
      if (j == 0) { PWAIT(2); ISS_G((g0 + 2) % 3, hcn, 0); }   // V0 landed, V1 flying
      else        { PWAIT(3); ISS_G(g0, hcn, 1); }             // V1 landed, G0' flying
      const unsigned short* b2b = w2s[j == 0 ? v0 : (v0 + 1) % 3];
      short8 af[4], bf[4];
      int c16 = j * 4 + quad;
#pragma unroll
      for (int mt = 0; mt < 4; mt++) {
        int r = wm * 64 + mt * 16 + l16;
        af[mt] = *(const short8*)(&hs[((unsigned)(r * 8 + (c16 ^ (r & 7)))) * 8]);
      }
#pragma unroll
      for (int nt = 0; nt < 4; nt++) {
        int r = wn * 64 + nt * 16 + l16;
        int inner = (((r & 1) << 2) | quad) ^ ((r >> 1) & 7);
        bf[nt] = *(const short8*)(&b2b[((unsigned)((r >> 1) * 8 + inner)) * 8]);
      }
      __builtin_amdgcn_s_setprio(1);
#pragma unroll
      for (int mt = 0; mt < 4; mt++)
#pragma unroll
        for (int nt = 0; nt < 4; nt++)
          acc2[mt][nt] = __builtin_amdgcn_mfma_f32_16x16x32_bf16(
              af[mt], bf[nt], acc2[mt][nt], 0, 0, 0);
      __builtin_amdgcn_s_setprio(0);
    }
  }
  // ---- epilogue: gate-weighted atomic accumulate (outstanding DMA harmless)
#pragma unroll
  for (int mt = 0; mt < 4; mt++) {
#pragma unroll
    for (int r4 = 0; r4 < 4; r4++) {
      int m = wm * 64 + mt * 16 + quad * 4 + r4;
      float wv = swgt[m];
      if (wv != 0.f) {
        int t = stok[m];
        float* op = out + (size_t)t * DOUT + wn * 64 + l16;
#pragma unroll
        for (int nt = 0; nt < 4; nt++)
          atomicAdd(op + nt * 16, acc2[mt][nt][r4] * wv);
      }
    }
  }
#undef ISS_G
#undef ISS_V
#undef PWAIT
}

extern "C" void kernel_launch(void* const* d_in, const int* in_sizes, int n_in,
                              void* d_out, int out_size, void* d_ws, size_t ws_size,
                              hipStream_t stream) {
  (void)in_sizes; (void)n_in; (void)ws_size;
  const float* x     = (const float*)d_in[0];
  const float* spike = (const float*)d_in[1];
  const float* Wr    = (const float*)d_in[2];
  const float* br    = (const float*)d_in[3];
  const float* W1    = (const float*)d_in[4];
  const float* b1    = (const float*)d_in[5];
  const float* W2    = (const float*)d_in[6];
  const float* b2    = (const float*)d_in[7];
  float* out = (float*)d_out;
  char* ws = (char*)d_ws;
  unsigned short* xb  = (unsigned short*)(ws + 0);          // 33,554,432
  unsigned short* w1t = (unsigned short*)(ws + 33554432);   // 10,485,760
  unsigned short* w2t = (unsigned short*)(ws + 44040192);   //  5,242,880
  float* wrt          = (float*)(ws + 49283072);            //     20,480
  int*   cnt          = (int*)(ws + 49303552);              //         64
  int*   tok          = (int*)(ws + 49303616);              //  1,310,720
  float* wgt          = (float*)(ws + 50614336);            //  1,310,720

  hipMemsetAsync(cnt, 0, 64, stream);
  hipMemsetAsync(out, 0, (size_t)out_size * sizeof(float), stream);
  k_transpose_wr<<<20, 256, 0, stream>>>(Wr, wrt);
  k_transpose_conv<<<dim3(16, 8, 10), 256, 0, stream>>>(W1, w1t, DIN, HID);
  k_transpose_conv<<<dim3(4, 16, 10), 256, 0, stream>>>(W2, w2t, HID, DOUT);
  k_router<<<512, 256, 0, stream>>>(x, spike, wrt, br, xb, cnt, tok, wgt);
  k_moe<<<dim3(256, NEXP), 512, 0, stream>>>(xb, w1t, w2t, b1, b2, cnt, tok, wgt, out);
}

// Round 3
// 403.291 us; speedup vs baseline: 1.2484x; 1.2484x over previous
//
#include <hip/hip_runtime.h>
#include <hip/hip_bf16.h>
#include <stdint.h>
#include <stddef.h>

typedef __attribute__((ext_vector_type(8))) short short8;
typedef __attribute__((ext_vector_type(4))) float f32x4;

#define NTOK 32768
#define DIN 512
#define HID 1024
#define DOUT 256
#define NEXP 10

__device__ __forceinline__ unsigned short f2bf(float f) {
  unsigned int u = __float_as_uint(f);
  u += 0x7fffu + ((u >> 16) & 1u);   // round-to-nearest-even
  return (unsigned short)(u >> 16);
}

// async 16B/lane global->LDS DMA (dest = wave-uniform base + lane*16)
__device__ __forceinline__ void gld16(void* lds, const void* g) {
  __builtin_amdgcn_global_load_lds(
      (const __attribute__((address_space(1))) unsigned int*)g,
      (__attribute__((address_space(3))) unsigned int*)lds, 16, 0, 0);
}

// ---------------- Wr transpose: [512][10] f32 -> [10][512] f32 -------------
__global__ __launch_bounds__(256) void k_transpose_wr(
    const float* __restrict__ wr, float* __restrict__ wrt) {
  int i = blockIdx.x * 256 + threadIdx.x;
  if (i < DIN * NEXP) {
    int d = i / NEXP, e = i % NEXP;
    wrt[e * DIN + d] = wr[i];
  }
}

// ---------- generic [E][R][C] f32 -> [E][C][R] bf16 (ushort bits) ----------
__global__ __launch_bounds__(256) void k_transpose_conv(
    const float* __restrict__ in, unsigned short* __restrict__ out, int R, int C) {
  __shared__ unsigned short tile[64][72];
  int tid = threadIdx.x;
  const float* ip = in + ((size_t)blockIdx.z * R + blockIdx.y * 64) * C + blockIdx.x * 64;
  int r = tid >> 2, c0 = (tid & 3) * 16;
  const float* p = ip + (size_t)r * C + c0;
#pragma unroll
  for (int j = 0; j < 16; j += 4) {
    float4 v = *(const float4*)(p + j);
    tile[r][c0 + j + 0] = f2bf(v.x);
    tile[r][c0 + j + 1] = f2bf(v.y);
    tile[r][c0 + j + 2] = f2bf(v.z);
    tile[r][c0 + j + 3] = f2bf(v.w);
  }
  __syncthreads();
  unsigned short* op = out + ((size_t)blockIdx.z * C + blockIdx.x * 64) * R + blockIdx.y * 64;
  int c = tid >> 2, r0 = (tid & 3) * 16;
  unsigned short* q = op + (size_t)c * R + r0;
  union { short8 v; unsigned short u[8]; } t0, t1;
#pragma unroll
  for (int j = 0; j < 8; j++) { t0.u[j] = tile[r0 + j][c]; t1.u[j] = tile[r0 + 8 + j][c]; }
  *(short8*)(q) = t0.v;
  *(short8*)(q + 8) = t1.v;
}

// ----------------- router: logits, softmax, top-2, expert lists ------------
__global__ __launch_bounds__(256) void k_router(
    const float* __restrict__ x, const float* __restrict__ spike,
    const float* __restrict__ wrt, const float* __restrict__ br,
    unsigned short* __restrict__ xb, int* __restrict__ cnt,
    int* __restrict__ tok, float* __restrict__ wgt) {
  __shared__ int s_i0[64], s_i1[64];
  __shared__ float s_w0[64], s_w1[64];
  __shared__ int hist[NEXP], base_[NEXP], loc[NEXP];
  int tid = threadIdx.x, wave = tid >> 6, lane = tid & 63;
  if (tid < NEXP) { hist[tid] = 0; loc[tid] = 0; }
  __syncthreads();
  for (int t = 0; t < 16; t++) {
    int slot = wave * 16 + t;
    int b = blockIdx.x * 64 + slot;
    const float* xr = x + (size_t)b * DIN;
    float xv[8];
#pragma unroll
    for (int k = 0; k < 8; k++) xv[k] = xr[lane + 64 * k];   // coalesced
    unsigned short* xo = xb + (size_t)b * DIN;
#pragma unroll
    for (int k = 0; k < 8; k++) xo[lane + 64 * k] = f2bf(xv[k]);
    float lg[NEXP];
#pragma unroll
    for (int e = 0; e < NEXP; e++) {
      const float* w = wrt + e * DIN;
      float s = 0.f;
#pragma unroll
      for (int k = 0; k < 8; k++) s += xv[k] * w[lane + 64 * k];
      lg[e] = s;
    }
#pragma unroll
    for (int off = 32; off > 0; off >>= 1) {
#pragma unroll
      for (int e = 0; e < NEXP; e++) lg[e] += __shfl_xor(lg[e], off);
    }
    float sv = spike[(size_t)b * 16 + (lane & 15)];
    sv += __shfl_xor(sv, 8); sv += __shfl_xor(sv, 4);
    sv += __shfl_xor(sv, 2); sv += __shfl_xor(sv, 1);
    float avg = sv * 0.0625f;
#pragma unroll
    for (int e = 0; e < NEXP; e++) lg[e] += br[e];
    lg[8] += avg; lg[9] += avg;
    float mx = lg[0];
#pragma unroll
    for (int e = 1; e < NEXP; e++) mx = fmaxf(mx, lg[e]);
    float p[NEXP], ps = 0.f;
#pragma unroll
    for (int e = 0; e < NEXP; e++) { p[e] = __expf(lg[e] - mx); ps += p[e]; }
    int i0 = 0; float p0 = p[0];
#pragma unroll
    for (int e = 1; e < NEXP; e++) if (p[e] > p0) { p0 = p[e]; i0 = e; }
    float p1 = -1.f; int i1 = 0;
#pragma unroll
    for (int e = 0; e < NEXP; e++) if (e != i0 && p[e] > p1) { p1 = p[e]; i1 = e; }
    float inv = 1.f / (p0 + p1 + ps * 1e-9f);
    if (lane == 0) {
      s_i0[slot] = i0; s_i1[slot] = i1;
      s_w0[slot] = p0 * inv; s_w1[slot] = p1 * inv;
      atomicAdd(&hist[i0], 1); atomicAdd(&hist[i1], 1);
    }
  }
  __syncthreads();
  if (tid < NEXP) base_[tid] = atomicAdd(&cnt[tid], hist[tid]);
  __syncthreads();
  if (tid < 64) {
    int b = blockIdx.x * 64 + tid;
    int i0 = s_i0[tid], i1 = s_i1[tid];
    int s0 = base_[i0] + atomicAdd(&loc[i0], 1);
    tok[i0 * NTOK + s0] = b; wgt[i0 * NTOK + s0] = s_w0[tid];
    int s1 = base_[i1] + atomicAdd(&loc[i1], 1);
    tok[i1 * NTOK + s1] = b; wgt[i1 * NTOK + s1] = s_w1[tid];
  }
}

// --------- fused grouped expert kernel: out += w * (relu(x W1 + b1) W2 + b2)
// Round-0 body (proven best) + compacted balanced work queue: each block
// grid-strides over the exact active tile list (no early-exit dead blocks,
// no per-expert dispatch bursts). Tile M=64 x N=256, HC=128, BK=64.
// 4 waves 2x2. LDS 74 KB -> 2 blocks/CU.
__global__ __launch_bounds__(256, 2) void k_moe(
    const unsigned short* __restrict__ xb, const unsigned short* __restrict__ w1t,
    const unsigned short* __restrict__ w2t, const float* __restrict__ b1,
    const float* __restrict__ b2, const int* __restrict__ cnt,
    const int* __restrict__ tok, const float* __restrict__ wgt,
    float* __restrict__ out) {
  __shared__ unsigned short xa[64 * 64];     //  8 KB  x-tile   [64 tok x 64 k]
  __shared__ unsigned short b1s[128 * 64];   // 16 KB  W1 tile  [128 h  x 64 k]
  __shared__ unsigned short b2s[256 * 64];   // 32 KB  W2 tile  [256 o  x 64 k]
  __shared__ unsigned short hs[64 * 128];    // 16 KB  h chunk  [64 tok x 128 h]
  __shared__ int stok[64];
  __shared__ float swgt[64];
  int tid = threadIdx.x;
  int wave = tid >> 6, lane = tid & 63, quad = lane >> 4, l16 = lane & 15;
  int wm = wave & 1, wn = wave >> 1;
  int srow = tid >> 3;                          // 0..31
  int c8 = (tid & 7) ^ (srow & 7);              // inverse XOR swizzle on source

  // ---- per-expert tile prefix (uniform scalar math; compile-time indices)
  int start_[NEXP + 1];
  start_[0] = 0;
#pragma unroll
  for (int i = 0; i < NEXP; i++) start_[i + 1] = start_[i] + ((cnt[i] + 63) >> 6);
  int T = start_[NEXP];

  for (int w = blockIdx.x; w < T; w += gridDim.x) {
    int e = 0;
#pragma unroll
    for (int i = 1; i < NEXP; i++) if (w >= start_[i]) e = i;
    int tile = w - start_[e];
    int n = cnt[e];

    __syncthreads();                 // prev tile's epilogue readers of stok/swgt done
    if (tid < 64) {
      int idx = tile * 64 + tid;
      bool v = idx < n;
      stok[tid] = v ? tok[e * NTOK + idx] : 0;
      swgt[tid] = v ? wgt[e * NTOK + idx] : 0.f;
    }
    __syncthreads();
    // ---- staging pointers (depend on stok)
    const unsigned short* gx0 = xb + (size_t)stok[srow] * DIN + c8 * 8;
    const unsigned short* gx1 = xb + (size_t)stok[32 + srow] * DIN + c8 * 8;
    const unsigned short* w1e = w1t + (size_t)e * HID * DIN;   // [h][d]
    const unsigned short* w2e = w2t + (size_t)e * DOUT * HID;  // [o][h]
    const unsigned short* gb1 = w1e + (size_t)srow * DIN + c8 * 8;
    const unsigned short* gb2 = w2e + (size_t)srow * HID + c8 * 8;
    // ---- fragment row indices
    int ra0 = wm * 32 + l16, ra1 = ra0 + 16;              // A rows (tokens)
    int rh0 = wn * 64 + l16;                              // GEMM1 B rows (h)
    int ro0 = wn * 128 + l16;                             // GEMM2 B rows (o)
    f32x4 acc2[2][8];
#pragma unroll
    for (int nt = 0; nt < 8; nt++) {
      float bv = b2[e * DOUT + wn * 128 + nt * 16 + l16];
      acc2[0][nt] = (f32x4){bv, bv, bv, bv};
      acc2[1][nt] = (f32x4){bv, bv, bv, bv};
    }
    for (int hc = 0; hc < 8; hc++) {
      // ================= GEMM1: h[64x128] = x[64x512] @ W1T-chunk =============
      f32x4 acc1[2][4];
#pragma unroll
      for (int nt = 0; nt < 4; nt++) {
        float bv = b1[e * HID + hc * 128 + wn * 64 + nt * 16 + l16];
        acc1[0][nt] = (f32x4){bv, bv, bv, bv};
        acc1[1][nt] = (f32x4){bv, bv, bv, bv};
      }
      for (int ks = 0; ks < 8; ks++) {
        __syncthreads();                         // prev readers of xa/b1s done
        gld16(xa + (size_t)tid * 8, gx0 + ks * 64);
        gld16(xa + ((size_t)tid + 256) * 8, gx1 + ks * 64);
#pragma unroll
        for (int s = 0; s < 4; s++)
          gld16(b1s + ((size_t)s * 256 + tid) * 8,
                gb1 + (size_t)hc * 128 * DIN + (size_t)s * 32 * DIN + ks * 64);
        __syncthreads();                         // DMA drained (vmcnt0 @ barrier)
#pragma unroll
        for (int ki2 = 0; ki2 < 2; ki2++) {
          int cq = ki2 * 4 + quad;
          short8 af[2], bf[4];
          af[0] = *(const short8*)(xa + (ra0 * 8 + (cq ^ (ra0 & 7))) * 8);
          af[1] = *(const short8*)(xa + (ra1 * 8 + (cq ^ (ra1 & 7))) * 8);
#pragma unroll
          for (int nt = 0; nt < 4; nt++) {
            int r = rh0 + nt * 16;
            bf[nt] = *(const short8*)(b1s + (r * 8 + (cq ^ (r & 7))) * 8);
          }
#pragma unroll
          for (int mt = 0; mt < 2; mt++)
#pragma unroll
            for (int nt = 0; nt < 4; nt++)
              acc1[mt][nt] = __builtin_amdgcn_mfma_f32_16x16x32_bf16(
                  af[mt], bf[nt], acc1[mt][nt], 0, 0, 0);
        }
      }
      // relu + bf16 -> swizzled h LDS (row = token, 16 chunks of 8)
#pragma unroll
      for (int mt = 0; mt < 2; mt++) {
#pragma unroll
        for (int nt = 0; nt < 4; nt++) {
          int col = wn * 64 + nt * 16 + l16;
          int c16 = col >> 3, co = col & 7;
#pragma unroll
          for (int r4 = 0; r4 < 4; r4++) {
            int r = wm * 32 + mt * 16 + quad * 4 + r4;
            float v = acc1[mt][nt][r4];
            hs[(r * 16 + (c16 ^ (r & 15))) * 8 + co] = f2bf(v > 0.f ? v : 0.f);
          }
        }
      }
      // ================= GEMM2: out[64x256] += h @ W2T-chunk ==================
      for (int k2 = 0; k2 < 2; k2++) {
        __syncthreads();                         // h written by all; prev b2s read
#pragma unroll
        for (int s = 0; s < 8; s++)
          gld16(b2s + ((size_t)s * 256 + tid) * 8,
                gb2 + (size_t)s * 32 * HID + hc * 128 + k2 * 64);
        __syncthreads();
#pragma unroll
        for (int ki2 = 0; ki2 < 2; ki2++) {
          int cq = ki2 * 4 + quad;
          int c16 = k2 * 8 + cq;
          short8 af[2], bf[8];
          af[0] = *(const short8*)(hs + (ra0 * 16 + (c16 ^ (ra0 & 15))) * 8);
          af[1] = *(const short8*)(hs + (ra1 * 16 + (c16 ^ (ra1 & 15))) * 8);
#pragma unroll
          for (int nt = 0; nt < 8; nt++) {
            int r = ro0 + nt * 16;
            bf[nt] = *(const short8*)(b2s + (r * 8 + (cq ^ (r & 7))) * 8);
          }
#pragma unroll
          for (int mt = 0; mt < 2; mt++)
#pragma unroll
            for (int nt = 0; nt < 8; nt++)
              acc2[mt][nt] = __builtin_amdgcn_mfma_f32_16x16x32_bf16(
                  af[mt], bf[nt], acc2[mt][nt], 0, 0, 0);
        }
      }
    }
    // ---- epilogue: gate-weighted atomic accumulate ----
#pragma unroll
    for (int mt = 0; mt < 2; mt++) {
#pragma unroll
      for (int r4 = 0; r4 < 4; r4++) {
        int m = wm * 32 + mt * 16 + quad * 4 + r4;
        float wv = swgt[m];
        if (wv != 0.f) {
          int t = stok[m];
          float* op = out + (size_t)t * DOUT + wn * 128 + l16;
#pragma unroll
          for (int nt = 0; nt < 8; nt++)
            atomicAdd(op + nt * 16, acc2[mt][nt][r4] * wv);
        }
      }
    }
  }
}

extern "C" void kernel_launch(void* const* d_in, const int* in_sizes, int n_in,
                              void* d_out, int out_size, void* d_ws, size_t ws_size,
                              hipStream_t stream) {
  (void)in_sizes; (void)n_in; (void)ws_size;
  const float* x     = (const float*)d_in[0];
  const float* spike = (const float*)d_in[1];
  const float* Wr    = (const float*)d_in[2];
  const float* br    = (const float*)d_in[3];
  const float* W1    = (const float*)d_in[4];
  const float* b1    = (const float*)d_in[5];
  const float* W2    = (const float*)d_in[6];
  const float* b2    = (const float*)d_in[7];
  float* out = (float*)d_out;
  char* ws = (char*)d_ws;
  unsigned short* xb  = (unsigned short*)(ws + 0);          // 33,554,432
  unsigned short* w1t = (unsigned short*)(ws + 33554432);   // 10,485,760
  unsigned short* w2t = (unsigned short*)(ws + 44040192);   //  5,242,880
  float* wrt          = (float*)(ws + 49283072);            //     20,480
  int*   cnt          = (int*)(ws + 49303552);              //         64
  int*   tok          = (int*)(ws + 49303616);              //  1,310,720
  float* wgt          = (float*)(ws + 50614336);            //  1,310,720

  hipMemsetAsync(cnt, 0, 64, stream);
  hipMemsetAsync(out, 0, (size_t)out_size * sizeof(float), stream);
  k_transpose_wr<<<20, 256, 0, stream>>>(Wr, wrt);
  k_transpose_conv<<<dim3(16, 8, 10), 256, 0, stream>>>(W1, w1t, DIN, HID);
  k_transpose_conv<<<dim3(4, 16, 10), 256, 0, stream>>>(W2, w2t, HID, DOUT);
  k_router<<<512, 256, 0, stream>>>(x, spike, wrt, br, xb, cnt, tok, wgt);
  k_moe<<<dim3(1024), 256, 0, stream>>>(xb, w1t, w2t, b1, b2, cnt, tok, wgt, out);
}